// Round 8
// baseline (640.338 us; speedup 1.0000x reference)
//
#include <hip/hip_runtime.h>
#include <cstdint>

// ---------------------------------------------------------------------------
// SelfAttention (QK-l2norm variant), MI355X/gfx950.
// R8: GEMM reverted to R2's proven 128x128/16x16 2-barrier body (181us, 0
// bank conflicts) with launch_bounds(256,4) for 4 blocks/CU. norml2 fused
// into gemm1 epilogue (R6-verified). Attention: KVBLK=64 -> 32KB LDS ->
// 4 blocks/CU. exp2 softmax + defer-rescale kept.
// Projections: Markidis hi/lo bf16 split (3 MFMAs) ~ fp32-accurate.
// ---------------------------------------------------------------------------

typedef __bf16 bfx8 __attribute__((ext_vector_type(8)));
typedef __bf16 bfx4 __attribute__((ext_vector_type(4)));
typedef float  f32x4 __attribute__((ext_vector_type(4)));

#define NB   4
#define NH   16
#define SEQ  2048
#define CH   1024
#define DD   64
#define MROWS (NB*SEQ)             /* 8192 */
#define BHLD  (NB*NH*SEQ*DD)       /* 8388608 */
#define LOG2E 1.44269504088896340736f

__device__ __forceinline__ void async16(void* lds, const void* g) {
  __builtin_amdgcn_global_load_lds((const __attribute__((address_space(1))) void*)g,
                                   (__attribute__((address_space(3))) void*)lds, 16, 0, 0);
}
__device__ __forceinline__ f32x4 mfma16(bfx8 a, bfx8 b, f32x4 c) {
  return __builtin_amdgcn_mfma_f32_16x16x32_bf16(a, b, c, 0, 0, 0);
}

extern "C" __device__ float __ocml_exp2_f32(float);
__device__ __forceinline__ float fexp2(float x) {
#if __has_builtin(__builtin_amdgcn_exp2f)
  return __builtin_amdgcn_exp2f(x);
#else
  return __ocml_exp2_f32(x);
#endif
}

// --------------------------- hi/lo split (Markidis) -------------------------
__global__ __launch_bounds__(256) void split_kernel(const float4* __restrict__ src,
                                                    __bf16* __restrict__ hi,
                                                    __bf16* __restrict__ lo, int n4) {
  int i = blockIdx.x * 256 + threadIdx.x;
  if (i >= n4) return;
  float4 v = src[i];
  float vv[4] = {v.x, v.y, v.z, v.w};
  bfx4 h, l;
  #pragma unroll
  for (int j = 0; j < 4; ++j) {
    __bf16 hb = (__bf16)vv[j];
    h[j] = hb;
    l[j] = (__bf16)(vv[j] - (float)hb);
  }
  *(bfx4*)(hi + 4*(size_t)i) = h;
  *(bfx4*)(lo + 4*(size_t)i) = l;
}

// --------------------------- bias nonzero scan ------------------------------
__global__ __launch_bounds__(256) void scan_nz(const uint4* __restrict__ p, int n4,
                                               int* __restrict__ flag) {
  unsigned acc = 0;
  const int stride = gridDim.x * 256;
  for (int i = blockIdx.x * 256 + threadIdx.x; i < n4; i += stride) {
    uint4 u = p[i];
    acc |= (u.x | u.y | u.z | u.w) & 0x7fffffffu;
  }
  if (acc) atomicOr(flag, 1);
}

// --------------------------- split-bf16 GEMM (NT) ---------------------------
// R2's proven body: 128x128 tile, 4 waves (2x2 of 64x64), BK=32, 32KB LDS,
// 2 barriers/K-step; launch_bounds(256,4) -> up to 4 blocks/CU for cross-
// block pipe overlap. 0-conflict chunk-XOR swizzle (verified involution).
// EPI==1: +concat(q_bias,0,v_bias), FUSED l2norm (+exp(scale)*LOG2E on q);
//         q/k -> [B,H,L,D] bf16, v -> [B,H,D,L].  EPI==2: +proj_b -> f32.
template<int EPI>
__global__ __launch_bounds__(256, 4) void gemm128(
    const __bf16* __restrict__ Agh, const __bf16* __restrict__ Agl,
    const __bf16* __restrict__ Bgh, const __bf16* __restrict__ Bgl,
    const int Ntiles, const int K,
    const float* __restrict__ biasA, const float* __restrict__ biasB,
    const float* __restrict__ scale_mul,
    float* __restrict__ outF, __bf16* __restrict__ outQ, __bf16* __restrict__ outV)
{
  __shared__ alignas(16) char lds[32768];   // Ah | Al | Bh | Bl, 8KB each
  const int tid = threadIdx.x;
  const int lane = tid & 63, w = tid >> 6;
  const int l15 = lane & 15, l4 = lane >> 4;
  const int nwg = (int)gridDim.x;
  const int wk = (int)(blockIdx.x & 7) * (nwg >> 3) + (int)(blockIdx.x >> 3); // nwg%8==0
  const int mt = wk / Ntiles, nt = wk % Ntiles;
  const int m0 = mt * 128, n0 = nt * 128;
  const int wm = (w >> 1) * 64, wn = (w & 1) * 64;

  const f32x4 zz = {0.f, 0.f, 0.f, 0.f};
  f32x4 acc[4][4];
  #pragma unroll
  for (int a = 0; a < 4; ++a)
    #pragma unroll
    for (int b = 0; b < 4; ++b) acc[a][b] = zz;

  // staging geometry: slot s = i*256+tid -> LDS byte s*16; row=s>>2,
  // logical k-chunk c = (s&3) ^ ((row>>1)&3)  (involution; read side matches)
  int st_row[2], st_c[2], st_lds[2];
  #pragma unroll
  for (int i = 0; i < 2; ++i) {
    const int s = i*256 + tid;
    st_row[i] = s >> 2;
    st_c[i]   = (s & 3) ^ ((st_row[i] >> 1) & 3);
    st_lds[i] = (i*256 + w*64) * 16;     // wave-uniform base; HW adds lane*16
  }

  for (int k0 = 0; k0 < K; k0 += 32) {
    __syncthreads();
    #pragma unroll
    for (int i = 0; i < 2; ++i) {
      const size_t ga = (size_t)(m0 + st_row[i]) * K + (size_t)(k0 + st_c[i]*8);
      const size_t gb = (size_t)(n0 + st_row[i]) * K + (size_t)(k0 + st_c[i]*8);
      async16(lds +         st_lds[i], Agh + ga);
      async16(lds +  8192 + st_lds[i], Agl + ga);
      async16(lds + 16384 + st_lds[i], Bgh + gb);
      async16(lds + 24576 + st_lds[i], Bgl + gb);
    }
    __syncthreads();

    bfx8 ah[4], al[4], bh[4], bl[4];
    #pragma unroll
    for (int f = 0; f < 4; ++f) {
      const int ra = wm + f*16 + l15;
      const int oa = ra*64 + ((l4 ^ ((ra >> 1) & 3)) * 16);
      ah[f] = *(const bfx8*)(lds + oa);
      al[f] = *(const bfx8*)(lds + 8192 + oa);
      const int rb = wn + f*16 + l15;
      const int ob = rb*64 + ((l4 ^ ((rb >> 1) & 3)) * 16);
      bh[f] = *(const bfx8*)(lds + 16384 + ob);
      bl[f] = *(const bfx8*)(lds + 24576 + ob);
    }
    __builtin_amdgcn_s_setprio(1);
    #pragma unroll
    for (int mf = 0; mf < 4; ++mf)
      #pragma unroll
      for (int nf = 0; nf < 4; ++nf) {
        acc[mf][nf] = mfma16(al[mf], bh[nf], acc[mf][nf]);
        acc[mf][nf] = mfma16(ah[mf], bl[nf], acc[mf][nf]);
        acc[mf][nf] = mfma16(ah[mf], bh[nf], acc[mf][nf]);
      }
    __builtin_amdgcn_s_setprio(0);
  }

  // ---- epilogue: C/D layout col=lane&15, row=4*(lane>>4)+reg ----
  if (EPI == 1) {
    // wave owns cols [n0+wn, +64) = exactly one (which, head) d-block
    const int gcb = n0 + wn;
    const int which = gcb >> 10;                 // 0 q, 1 k, 2 v
    const int hh = (gcb & (CH-1)) >> 6;
    float smul = 1.f;
    if (which == 0) smul = __expf(fminf(scale_mul[hh], 4.605170185988091f)) * LOG2E;
    #pragma unroll
    for (int mf = 0; mf < 4; ++mf)
      #pragma unroll
      for (int rg = 0; rg < 4; ++rg) {
        #pragma unroll
        for (int nf = 0; nf < 4; ++nf) {
          const int gc = gcb + nf*16 + l15;
          acc[mf][nf][rg] += (which == 0) ? biasA[gc]
                           : ((which == 2) ? biasB[gc - 2*CH] : 0.f);
        }
        const int gr = m0 + wm + mf*16 + 4*l4 + rg;
        const int bb = gr >> 11, ll = gr & (SEQ-1);
        float sc = 1.f;
        if (which < 2) {   // fused l2norm over the 64-col head block (f32!)
          float ss = 0.f;
          #pragma unroll
          for (int nf = 0; nf < 4; ++nf) ss += acc[mf][nf][rg] * acc[mf][nf][rg];
          ss += __shfl_xor(ss, 1); ss += __shfl_xor(ss, 2);
          ss += __shfl_xor(ss, 4); ss += __shfl_xor(ss, 8);
          sc = smul / fmaxf(sqrtf(ss), 1e-12f);
        }
        #pragma unroll
        for (int nf = 0; nf < 4; ++nf) {
          const float v = acc[mf][nf][rg] * sc;
          const int dd = nf*16 + l15;
          if (which < 2)
            outQ[(size_t)which*BHLD + ((size_t)((bb*NH + hh)*SEQ) + ll)*DD + dd] = (__bf16)v;
          else
            outV[((size_t)(bb*NH + hh)*DD + dd)*SEQ + ll] = (__bf16)v;
        }
      }
  } else {
    #pragma unroll
    for (int mf = 0; mf < 4; ++mf)
      #pragma unroll
      for (int nf = 0; nf < 4; ++nf)
        #pragma unroll
        for (int rg = 0; rg < 4; ++rg) {
          const int gr = m0 + wm + mf*16 + 4*l4 + rg;
          const int gc = n0 + wn + nf*16 + l15;
          outF[(size_t)gr*CH + gc] = acc[mf][nf][rg] + biasA[gc];
        }
  }
}

// --------------------------- flash attention (bf16, swapped ops) ------------
// KVBLK=64: Ks[64k][128B] 8KB, Vt[64d][128B] 8KB, Ps 4x4KB = 32KB total
// -> 4 blocks/CU. Scores in log2-units (LOG2E folded upstream); exp2 softmax;
// defer-rescale while __all(mx - m <= 12).
__global__ __launch_bounds__(256, 4) void attn_kernel(
    const __bf16* __restrict__ qn, const __bf16* __restrict__ kn,
    const __bf16* __restrict__ vtg,
    const float* __restrict__ bias, const int* __restrict__ flag,
    __bf16* __restrict__ ao_hi, __bf16* __restrict__ ao_lo)
{
  __shared__ alignas(16) char Ks[8192];
  __shared__ alignas(16) char Vt[8192];
  __shared__ alignas(16) char Ps[16384];

  const int tid = threadIdx.x, lane = tid & 63, w = tid >> 6;
  const int l15 = lane & 15, l4 = lane >> 4;
  const int wk = (int)(blockIdx.x & 7) * 128 + (int)(blockIdx.x >> 3);
  const int qt = wk & 15, h = (wk >> 4) & 15, b = wk >> 8;
  const size_t bh = ((size_t)(b*NH + h)) * SEQ * DD;
  const int hasbias = *flag;
  char* Pw = Ps + w*4096;

  // Q fragments (B-operand: col=lane&15=q, k=8*(lane>>4)+j)
  bfx8 Qf[2][2];
  const int q0 = qt*128 + w*32;
  #pragma unroll
  for (int mf = 0; mf < 2; ++mf)
    #pragma unroll
    for (int kd = 0; kd < 2; ++kd)
      Qf[mf][kd] = *(const bfx8*)(qn + bh + (size_t)(q0 + mf*16 + l15)*DD + kd*32 + l4*8);

  const f32x4 zz = {0.f, 0.f, 0.f, 0.f};
  f32x4 O[2][4];
  float m_[2] = {-1e30f, -1e30f}, l_[2] = {0.f, 0.f};
  #pragma unroll
  for (int mf = 0; mf < 2; ++mf)
    #pragma unroll
    for (int nd = 0; nd < 4; ++nd) O[mf][nd] = zz;

  for (int t = 0; t < 32; ++t) {
    __syncthreads();   // all waves done with Ks/Vt (+Ps) of previous tile

    // ---- stage K tile [64k][64d] (async, pre-swizzled source; 8 chunks/row)
    const __bf16* ksrc = kn + bh + (size_t)t*64*DD;
    #pragma unroll
    for (int i = 0; i < 2; ++i) {
      const int s = i*256 + tid;
      const int row = s >> 3;
      const int c = (s & 7) ^ (row & 7);
      async16(Ks + (size_t)(i*256 + w*64)*16, ksrc + (size_t)row*DD + c*8);
    }
    // ---- stage V^T tile [64d][64k] (async, pre-swizzled source) ----
    const __bf16* vsrc = vtg + bh + (size_t)t*64;
    #pragma unroll
    for (int i = 0; i < 2; ++i) {
      const int s = i*256 + tid;
      const int row = s >> 3;                     // d
      const int c = (s & 7) ^ (row & 7);
      async16(Vt + (size_t)(i*256 + w*64)*16, vsrc + (size_t)row*SEQ + c*8);
    }
    __syncthreads();   // vmcnt drained by compiler before barrier

    // ---- S^T = K Q^T : lane holds q=l15(+16mf), k=16nf+4*l4+rg ----
    f32x4 ST[2][4];
    __builtin_amdgcn_s_setprio(1);
    #pragma unroll
    for (int nf = 0; nf < 4; ++nf) {
      const int r = nf*16 + l15;
      const bfx8 K0 = *(const bfx8*)(Ks + r*128 + ((l4 ^ (r & 7)) * 16));
      const bfx8 K1 = *(const bfx8*)(Ks + r*128 + (((4 + l4) ^ (r & 7)) * 16));
      #pragma unroll
      for (int mf = 0; mf < 2; ++mf) {
        f32x4 sacc = mfma16(K0, Qf[mf][0], zz);
        ST[mf][nf] = mfma16(K1, Qf[mf][1], sacc);
      }
    }
    __builtin_amdgcn_s_setprio(0);

    if (hasbias) {
      #pragma unroll
      for (int mf = 0; mf < 2; ++mf) {
        const size_t qg = (size_t)(q0 + mf*16 + l15);
        const float* bp = bias + qg*SEQ + (size_t)t*64;
        #pragma unroll
        for (int nf = 0; nf < 4; ++nf)
          #pragma unroll
          for (int rg = 0; rg < 4; ++rg)
            ST[mf][nf][rg] += bp[nf*16 + 4*l4 + rg] * LOG2E;
      }
    }

    // ---- online softmax (log2-units; defer-rescale) ----
    #pragma unroll
    for (int mf = 0; mf < 2; ++mf) {
      f32x4 mv = ST[mf][0];
      #pragma unroll
      for (int nf = 1; nf < 4; ++nf)
        #pragma unroll
        for (int rg = 0; rg < 4; ++rg) mv[rg] = fmaxf(mv[rg], ST[mf][nf][rg]);
      float mx = fmaxf(fmaxf(mv[0], mv[1]), fmaxf(mv[2], mv[3]));
      mx = fmaxf(mx, __shfl_xor(mx, 16));
      mx = fmaxf(mx, __shfl_xor(mx, 32));
      const bool skip = __all(mx - m_[mf] <= 12.0f) != 0;
      const float mn = skip ? m_[mf] : fmaxf(m_[mf], mx);
      f32x4 sv = zz;
      #pragma unroll
      for (int nf = 0; nf < 4; ++nf) {
        #pragma unroll
        for (int rg = 0; rg < 4; ++rg) {
          const float pv = fexp2(ST[mf][nf][rg] - mn);
          ST[mf][nf][rg] = pv;
          sv[rg] += pv;
        }
      }
      float rs = (sv[0] + sv[1]) + (sv[2] + sv[3]);
      rs += __shfl_xor(rs, 16);
      rs += __shfl_xor(rs, 32);
      if (skip) {
        l_[mf] += rs;
      } else {
        const float corr = fexp2(m_[mf] - mn);
        l_[mf] = l_[mf] * corr + rs;
        m_[mf] = mn;
        #pragma unroll
        for (int nd = 0; nd < 4; ++nd)
          #pragma unroll
          for (int rg = 0; rg < 4; ++rg) O[mf][nd][rg] *= corr;
      }

      // ---- P -> Ps[q=32][k=64] per wave, b64 swizzled writes ----
      const int row = mf*16 + l15;
      #pragma unroll
      for (int nf = 0; nf < 4; ++nf) {
        bfx4 p4;
        #pragma unroll
        for (int rg = 0; rg < 4; ++rg) p4[rg] = (__bf16)ST[mf][nf][rg];
        const int cpos = (2*nf + (l4 >> 1)) ^ (row & 7);
        *(bfx4*)(Pw + row*128 + cpos*16 + (l4 & 1)*8) = p4;
      }
    }

    // ---- O^T += V^T P : lane holds q=l15(+16mf), d=16nd+4*l4+rg ----
    __builtin_amdgcn_s_setprio(1);
    #pragma unroll
    for (int kk = 0; kk < 2; ++kk) {
      bfx8 Pf[2];
      #pragma unroll
      for (int mf = 0; mf < 2; ++mf) {
        const int row = mf*16 + l15;
        Pf[mf] = *(const bfx8*)(Pw + row*128 + (((4*kk + l4) ^ (row & 7)) * 16));
      }
      #pragma unroll
      for (int nd = 0; nd < 4; ++nd) {
        const int dr = nd*16 + l15;
        const bfx8 Vf = *(const bfx8*)(Vt + dr*128 + (((4*kk + l4) ^ (dr & 7)) * 16));
        #pragma unroll
        for (int mf = 0; mf < 2; ++mf)
          O[mf][nd] = mfma16(Vf, Pf[mf], O[mf][nd]);
      }
    }
    __builtin_amdgcn_s_setprio(0);
  }

  // ---- epilogue: O/l, hi/lo bf16 split, bfx4 stores (d consecutive) ----
  #pragma unroll
  for (int mf = 0; mf < 2; ++mf) {
    const float inv = 1.f / l_[mf];
    const int qg = q0 + mf*16 + l15;
    #pragma unroll
    for (int nd = 0; nd < 4; ++nd) {
      bfx4 hb, lb;
      #pragma unroll
      for (int rg = 0; rg < 4; ++rg) {
        const float v = O[mf][nd][rg] * inv;
        hb[rg] = (__bf16)v;
        lb[rg] = (__bf16)(v - (float)hb[rg]);
      }
      const size_t idx = ((size_t)(b*SEQ + qg))*CH + h*DD + nd*16 + 4*l4;
      *(bfx4*)(ao_hi + idx) = hb;
      *(bfx4*)(ao_lo + idx) = lb;
    }
  }
}

// ---------------------------------------------------------------------------
extern "C" void kernel_launch(void* const* d_in, const int* in_sizes, int n_in,
                              void* d_out, int out_size, void* d_ws, size_t ws_size,
                              hipStream_t stream) {
  const float* x         = (const float*)d_in[0];
  const float* attn_bias = (const float*)d_in[1];
  const float* qkv_w     = (const float*)d_in[2];
  const float* q_bias    = (const float*)d_in[3];
  const float* v_bias    = (const float*)d_in[4];
  const float* scale_mul = (const float*)d_in[5];
  const float* proj_w    = (const float*)d_in[6];
  const float* proj_b    = (const float*)d_in[7];
  float* out = (float*)d_out;

  char* ws = (char*)d_ws;
  size_t off = 0;
  auto alloc = [&](size_t n) { char* p = ws + off; off += (n + 255) & ~(size_t)255; return p; };
  __bf16* x_h  = (__bf16*)alloc((size_t)MROWS*CH*2);
  __bf16* x_l  = (__bf16*)alloc((size_t)MROWS*CH*2);
  __bf16* w_h  = (__bf16*)alloc((size_t)3*CH*CH*2);
  __bf16* w_l  = (__bf16*)alloc((size_t)3*CH*CH*2);
  __bf16* p_h  = (__bf16*)alloc((size_t)CH*CH*2);
  __bf16* p_l  = (__bf16*)alloc((size_t)CH*CH*2);
  __bf16* qkvn = (__bf16*)alloc((size_t)2*BHLD*2);   // q,k [B,H,L,D] (normalized)
  __bf16* vt   = (__bf16*)alloc((size_t)BHLD*2);     // v   [B,H,D,L]
  __bf16* ao_h = (__bf16*)alloc((size_t)MROWS*CH*2);
  __bf16* ao_l = (__bf16*)alloc((size_t)MROWS*CH*2);
  int*    flag = (int*)alloc(256);

  split_kernel<<<MROWS*CH/4/256, 256, 0, stream>>>((const float4*)x, x_h, x_l, MROWS*CH/4);
  split_kernel<<<3*CH*CH/4/256, 256, 0, stream>>>((const float4*)qkv_w, w_h, w_l, 3*CH*CH/4);
  split_kernel<<<CH*CH/4/256, 256, 0, stream>>>((const float4*)proj_w, p_h, p_l, CH*CH/4);

  hipMemsetAsync(flag, 0, sizeof(int), stream);
  scan_nz<<<2048, 256, 0, stream>>>((const uint4*)attn_bias, SEQ*SEQ/4, flag);

  // GEMM1: [8192,3072] = x*qkv_w^T (+bias, +fused l2norm) -> q/k [B,H,L,D], v [B,H,D,L]
  gemm128<1><<<(MROWS/128)*(3*CH/128), 256, 0, stream>>>(
      x_h, x_l, w_h, w_l, 3*CH/128, CH, q_bias, v_bias, scale_mul,
      nullptr, qkvn, vt);

  attn_kernel<<<NB*NH*(SEQ/128), 256, 0, stream>>>(
      qkvn, qkvn + (size_t)BHLD, vt, attn_bias, flag, ao_h, ao_l);

  // GEMM2: d_out = attn_out * proj_w^T + proj_b
  gemm128<2><<<(MROWS/128)*(CH/128), 256, 0, stream>>>(
      ao_h, ao_l, p_h, p_l, CH/128, CH, proj_b, nullptr, nullptr,
      out, nullptr, nullptr);
}

// Round 9
// 376.582 us; speedup vs baseline: 1.7004x; 1.7004x over previous
//
#include <hip/hip_runtime.h>
#include <cstdint>

// ---------------------------------------------------------------------------
// SelfAttention (QK-l2norm variant), MI355X/gfx950.
// R9: de-risk round. GEMM = R2's proven 128x128 2-barrier body at
// launch_bounds(256,2) (R6/R8 lesson: (256,4) halves the VGPR budget ->
// catastrophic spill; never request 4 waves/SIMD with a 64-AGPR acc).
// norml2 fused into gemm1 epilogue (R8-verified numerics). Attention =
// R8's KVBLK=64 / 32KB-LDS body at (256,2) so occupancy comes from low
// VGPR+LDS, not from a forced cap. exp2 softmax + defer-rescale.
// Projections: Markidis hi/lo bf16 split (3 MFMAs) ~ fp32-accurate.
// ---------------------------------------------------------------------------

typedef __bf16 bfx8 __attribute__((ext_vector_type(8)));
typedef __bf16 bfx4 __attribute__((ext_vector_type(4)));
typedef float  f32x4 __attribute__((ext_vector_type(4)));

#define NB   4
#define NH   16
#define SEQ  2048
#define CH   1024
#define DD   64
#define MROWS (NB*SEQ)             /* 8192 */
#define BHLD  (NB*NH*SEQ*DD)       /* 8388608 */
#define LOG2E 1.44269504088896340736f

__device__ __forceinline__ void async16(void* lds, const void* g) {
  __builtin_amdgcn_global_load_lds((const __attribute__((address_space(1))) void*)g,
                                   (__attribute__((address_space(3))) void*)lds, 16, 0, 0);
}
__device__ __forceinline__ f32x4 mfma16(bfx8 a, bfx8 b, f32x4 c) {
  return __builtin_amdgcn_mfma_f32_16x16x32_bf16(a, b, c, 0, 0, 0);
}

extern "C" __device__ float __ocml_exp2_f32(float);
__device__ __forceinline__ float fexp2(float x) {
#if __has_builtin(__builtin_amdgcn_exp2f)
  return __builtin_amdgcn_exp2f(x);
#else
  return __ocml_exp2_f32(x);
#endif
}

// --------------------------- hi/lo split (Markidis) -------------------------
__global__ __launch_bounds__(256) void split_kernel(const float4* __restrict__ src,
                                                    __bf16* __restrict__ hi,
                                                    __bf16* __restrict__ lo, int n4) {
  int i = blockIdx.x * 256 + threadIdx.x;
  if (i >= n4) return;
  float4 v = src[i];
  float vv[4] = {v.x, v.y, v.z, v.w};
  bfx4 h, l;
  #pragma unroll
  for (int j = 0; j < 4; ++j) {
    __bf16 hb = (__bf16)vv[j];
    h[j] = hb;
    l[j] = (__bf16)(vv[j] - (float)hb);
  }
  *(bfx4*)(hi + 4*(size_t)i) = h;
  *(bfx4*)(lo + 4*(size_t)i) = l;
}

// --------------------------- bias nonzero scan ------------------------------
__global__ __launch_bounds__(256) void scan_nz(const uint4* __restrict__ p, int n4,
                                               int* __restrict__ flag) {
  unsigned acc = 0;
  const int stride = gridDim.x * 256;
  for (int i = blockIdx.x * 256 + threadIdx.x; i < n4; i += stride) {
    uint4 u = p[i];
    acc |= (u.x | u.y | u.z | u.w) & 0x7fffffffu;
  }
  if (acc) atomicOr(flag, 1);
}

// --------------------------- split-bf16 GEMM (NT) ---------------------------
// R2's proven body: 128x128 tile, 4 waves (2x2 of 64x64), BK=32, 32KB LDS,
// 2 barriers/K-step, launch_bounds(256,2). 0-conflict chunk-XOR swizzle.
// EPI==1: +concat(q_bias,0,v_bias), FUSED l2norm (+exp(scale)*LOG2E on q);
//         q/k -> [B,H,L,D] bf16, v -> [B,H,D,L].  EPI==2: +proj_b -> f32.
template<int EPI>
__global__ __launch_bounds__(256, 2) void gemm128(
    const __bf16* __restrict__ Agh, const __bf16* __restrict__ Agl,
    const __bf16* __restrict__ Bgh, const __bf16* __restrict__ Bgl,
    const int Ntiles, const int K,
    const float* __restrict__ biasA, const float* __restrict__ biasB,
    const float* __restrict__ scale_mul,
    float* __restrict__ outF, __bf16* __restrict__ outQ, __bf16* __restrict__ outV)
{
  __shared__ alignas(16) char lds[32768];   // Ah | Al | Bh | Bl, 8KB each
  const int tid = threadIdx.x;
  const int lane = tid & 63, w = tid >> 6;
  const int l15 = lane & 15, l4 = lane >> 4;
  const int nwg = (int)gridDim.x;
  const int wk = (int)(blockIdx.x & 7) * (nwg >> 3) + (int)(blockIdx.x >> 3); // nwg%8==0
  const int mt = wk / Ntiles, nt = wk % Ntiles;
  const int m0 = mt * 128, n0 = nt * 128;
  const int wm = (w >> 1) * 64, wn = (w & 1) * 64;

  const f32x4 zz = {0.f, 0.f, 0.f, 0.f};
  f32x4 acc[4][4];
  #pragma unroll
  for (int a = 0; a < 4; ++a)
    #pragma unroll
    for (int b = 0; b < 4; ++b) acc[a][b] = zz;

  // staging geometry: slot s = i*256+tid -> LDS byte s*16; row=s>>2,
  // logical k-chunk c = (s&3) ^ ((row>>1)&3)  (involution; read side matches)
  int st_row[2], st_c[2], st_lds[2];
  #pragma unroll
  for (int i = 0; i < 2; ++i) {
    const int s = i*256 + tid;
    st_row[i] = s >> 2;
    st_c[i]   = (s & 3) ^ ((st_row[i] >> 1) & 3);
    st_lds[i] = (i*256 + w*64) * 16;     // wave-uniform base; HW adds lane*16
  }

  for (int k0 = 0; k0 < K; k0 += 32) {
    __syncthreads();
    #pragma unroll
    for (int i = 0; i < 2; ++i) {
      const size_t ga = (size_t)(m0 + st_row[i]) * K + (size_t)(k0 + st_c[i]*8);
      const size_t gb = (size_t)(n0 + st_row[i]) * K + (size_t)(k0 + st_c[i]*8);
      async16(lds +         st_lds[i], Agh + ga);
      async16(lds +  8192 + st_lds[i], Agl + ga);
      async16(lds + 16384 + st_lds[i], Bgh + gb);
      async16(lds + 24576 + st_lds[i], Bgl + gb);
    }
    __syncthreads();

    bfx8 ah[4], al[4], bh[4], bl[4];
    #pragma unroll
    for (int f = 0; f < 4; ++f) {
      const int ra = wm + f*16 + l15;
      const int oa = ra*64 + ((l4 ^ ((ra >> 1) & 3)) * 16);
      ah[f] = *(const bfx8*)(lds + oa);
      al[f] = *(const bfx8*)(lds + 8192 + oa);
      const int rb = wn + f*16 + l15;
      const int ob = rb*64 + ((l4 ^ ((rb >> 1) & 3)) * 16);
      bh[f] = *(const bfx8*)(lds + 16384 + ob);
      bl[f] = *(const bfx8*)(lds + 24576 + ob);
    }
    __builtin_amdgcn_s_setprio(1);
    #pragma unroll
    for (int mf = 0; mf < 4; ++mf)
      #pragma unroll
      for (int nf = 0; nf < 4; ++nf) {
        acc[mf][nf] = mfma16(al[mf], bh[nf], acc[mf][nf]);
        acc[mf][nf] = mfma16(ah[mf], bl[nf], acc[mf][nf]);
        acc[mf][nf] = mfma16(ah[mf], bh[nf], acc[mf][nf]);
      }
    __builtin_amdgcn_s_setprio(0);
  }

  // ---- epilogue: C/D layout col=lane&15, row=4*(lane>>4)+reg ----
  if (EPI == 1) {
    // wave owns cols [n0+wn, +64) = exactly one (which, head) d-block
    const int gcb = n0 + wn;
    const int which = gcb >> 10;                 // 0 q, 1 k, 2 v
    const int hh = (gcb & (CH-1)) >> 6;
    float smul = 1.f;
    if (which == 0) smul = __expf(fminf(scale_mul[hh], 4.605170185988091f)) * LOG2E;
    #pragma unroll
    for (int mf = 0; mf < 4; ++mf)
      #pragma unroll
      for (int rg = 0; rg < 4; ++rg) {
        #pragma unroll
        for (int nf = 0; nf < 4; ++nf) {
          const int gc = gcb + nf*16 + l15;
          acc[mf][nf][rg] += (which == 0) ? biasA[gc]
                           : ((which == 2) ? biasB[gc - 2*CH] : 0.f);
        }
        const int gr = m0 + wm + mf*16 + 4*l4 + rg;
        const int bb = gr >> 11, ll = gr & (SEQ-1);
        float sc = 1.f;
        if (which < 2) {   // fused l2norm over the 64-col head block (f32!)
          float ss = 0.f;
          #pragma unroll
          for (int nf = 0; nf < 4; ++nf) ss += acc[mf][nf][rg] * acc[mf][nf][rg];
          ss += __shfl_xor(ss, 1); ss += __shfl_xor(ss, 2);
          ss += __shfl_xor(ss, 4); ss += __shfl_xor(ss, 8);
          sc = smul / fmaxf(sqrtf(ss), 1e-12f);
        }
        #pragma unroll
        for (int nf = 0; nf < 4; ++nf) {
          const float v = acc[mf][nf][rg] * sc;
          const int dd = nf*16 + l15;
          if (which < 2)
            outQ[(size_t)which*BHLD + ((size_t)((bb*NH + hh)*SEQ) + ll)*DD + dd] = (__bf16)v;
          else
            outV[((size_t)(bb*NH + hh)*DD + dd)*SEQ + ll] = (__bf16)v;
        }
      }
  } else {
    #pragma unroll
    for (int mf = 0; mf < 4; ++mf)
      #pragma unroll
      for (int nf = 0; nf < 4; ++nf)
        #pragma unroll
        for (int rg = 0; rg < 4; ++rg) {
          const int gr = m0 + wm + mf*16 + 4*l4 + rg;
          const int gc = n0 + wn + nf*16 + l15;
          outF[(size_t)gr*CH + gc] = acc[mf][nf][rg] + biasA[gc];
        }
  }
}

// --------------------------- flash attention (bf16, swapped ops) ------------
// KVBLK=64: Ks 8KB, Vt 8KB, Ps 4x4KB = 32KB total; launch_bounds(256,2) so
// occupancy comes from LDS/VGPR, not a forced cap. Scores in log2-units;
// exp2 softmax; defer-rescale while __all(mx - m <= 12).
__global__ __launch_bounds__(256, 2) void attn_kernel(
    const __bf16* __restrict__ qn, const __bf16* __restrict__ kn,
    const __bf16* __restrict__ vtg,
    const float* __restrict__ bias, const int* __restrict__ flag,
    __bf16* __restrict__ ao_hi, __bf16* __restrict__ ao_lo)
{
  __shared__ alignas(16) char Ks[8192];
  __shared__ alignas(16) char Vt[8192];
  __shared__ alignas(16) char Ps[16384];

  const int tid = threadIdx.x, lane = tid & 63, w = tid >> 6;
  const int l15 = lane & 15, l4 = lane >> 4;
  const int wk = (int)(blockIdx.x & 7) * 128 + (int)(blockIdx.x >> 3);
  const int qt = wk & 15, h = (wk >> 4) & 15, b = wk >> 8;
  const size_t bh = ((size_t)(b*NH + h)) * SEQ * DD;
  const int hasbias = *flag;
  char* Pw = Ps + w*4096;

  // Q fragments (B-operand: col=lane&15=q, k=8*(lane>>4)+j)
  bfx8 Qf[2][2];
  const int q0 = qt*128 + w*32;
  #pragma unroll
  for (int mf = 0; mf < 2; ++mf)
    #pragma unroll
    for (int kd = 0; kd < 2; ++kd)
      Qf[mf][kd] = *(const bfx8*)(qn + bh + (size_t)(q0 + mf*16 + l15)*DD + kd*32 + l4*8);

  const f32x4 zz = {0.f, 0.f, 0.f, 0.f};
  f32x4 O[2][4];
  float m_[2] = {-1e30f, -1e30f}, l_[2] = {0.f, 0.f};
  #pragma unroll
  for (int mf = 0; mf < 2; ++mf)
    #pragma unroll
    for (int nd = 0; nd < 4; ++nd) O[mf][nd] = zz;

  for (int t = 0; t < 32; ++t) {
    __syncthreads();   // all waves done with Ks/Vt (+Ps) of previous tile

    // ---- stage K tile [64k][64d] (async, pre-swizzled source; 8 chunks/row)
    const __bf16* ksrc = kn + bh + (size_t)t*64*DD;
    #pragma unroll
    for (int i = 0; i < 2; ++i) {
      const int s = i*256 + tid;
      const int row = s >> 3;
      const int c = (s & 7) ^ (row & 7);
      async16(Ks + (size_t)(i*256 + w*64)*16, ksrc + (size_t)row*DD + c*8);
    }
    // ---- stage V^T tile [64d][64k] (async, pre-swizzled source) ----
    const __bf16* vsrc = vtg + bh + (size_t)t*64;
    #pragma unroll
    for (int i = 0; i < 2; ++i) {
      const int s = i*256 + tid;
      const int row = s >> 3;                     // d
      const int c = (s & 7) ^ (row & 7);
      async16(Vt + (size_t)(i*256 + w*64)*16, vsrc + (size_t)row*SEQ + c*8);
    }
    __syncthreads();   // vmcnt drained by compiler before barrier

    // ---- S^T = K Q^T : lane holds q=l15(+16mf), k=16nf+4*l4+rg ----
    f32x4 ST[2][4];
    __builtin_amdgcn_s_setprio(1);
    #pragma unroll
    for (int nf = 0; nf < 4; ++nf) {
      const int r = nf*16 + l15;
      const bfx8 K0 = *(const bfx8*)(Ks + r*128 + ((l4 ^ (r & 7)) * 16));
      const bfx8 K1 = *(const bfx8*)(Ks + r*128 + (((4 + l4) ^ (r & 7)) * 16));
      #pragma unroll
      for (int mf = 0; mf < 2; ++mf) {
        f32x4 sacc = mfma16(K0, Qf[mf][0], zz);
        ST[mf][nf] = mfma16(K1, Qf[mf][1], sacc);
      }
    }
    __builtin_amdgcn_s_setprio(0);

    if (hasbias) {
      #pragma unroll
      for (int mf = 0; mf < 2; ++mf) {
        const size_t qg = (size_t)(q0 + mf*16 + l15);
        const float* bp = bias + qg*SEQ + (size_t)t*64;
        #pragma unroll
        for (int nf = 0; nf < 4; ++nf)
          #pragma unroll
          for (int rg = 0; rg < 4; ++rg)
            ST[mf][nf][rg] += bp[nf*16 + 4*l4 + rg] * LOG2E;
      }
    }

    // ---- online softmax (log2-units; defer-rescale) ----
    #pragma unroll
    for (int mf = 0; mf < 2; ++mf) {
      f32x4 mv = ST[mf][0];
      #pragma unroll
      for (int nf = 1; nf < 4; ++nf)
        #pragma unroll
        for (int rg = 0; rg < 4; ++rg) mv[rg] = fmaxf(mv[rg], ST[mf][nf][rg]);
      float mx = fmaxf(fmaxf(mv[0], mv[1]), fmaxf(mv[2], mv[3]));
      mx = fmaxf(mx, __shfl_xor(mx, 16));
      mx = fmaxf(mx, __shfl_xor(mx, 32));
      const bool skip = __all(mx - m_[mf] <= 12.0f) != 0;
      const float mn = skip ? m_[mf] : fmaxf(m_[mf], mx);
      f32x4 sv = zz;
      #pragma unroll
      for (int nf = 0; nf < 4; ++nf) {
        #pragma unroll
        for (int rg = 0; rg < 4; ++rg) {
          const float pv = fexp2(ST[mf][nf][rg] - mn);
          ST[mf][nf][rg] = pv;
          sv[rg] += pv;
        }
      }
      float rs = (sv[0] + sv[1]) + (sv[2] + sv[3]);
      rs += __shfl_xor(rs, 16);
      rs += __shfl_xor(rs, 32);
      if (skip) {
        l_[mf] += rs;
      } else {
        const float corr = fexp2(m_[mf] - mn);
        l_[mf] = l_[mf] * corr + rs;
        m_[mf] = mn;
        #pragma unroll
        for (int nd = 0; nd < 4; ++nd)
          #pragma unroll
          for (int rg = 0; rg < 4; ++rg) O[mf][nd][rg] *= corr;
      }

      // ---- P -> Ps[q=32][k=64] per wave, b64 swizzled writes ----
      const int row = mf*16 + l15;
      #pragma unroll
      for (int nf = 0; nf < 4; ++nf) {
        bfx4 p4;
        #pragma unroll
        for (int rg = 0; rg < 4; ++rg) p4[rg] = (__bf16)ST[mf][nf][rg];
        const int cpos = (2*nf + (l4 >> 1)) ^ (row & 7);
        *(bfx4*)(Pw + row*128 + cpos*16 + (l4 & 1)*8) = p4;
      }
    }

    // ---- O^T += V^T P : lane holds q=l15(+16mf), d=16nd+4*l4+rg ----
    __builtin_amdgcn_s_setprio(1);
    #pragma unroll
    for (int kk = 0; kk < 2; ++kk) {
      bfx8 Pf[2];
      #pragma unroll
      for (int mf = 0; mf < 2; ++mf) {
        const int row = mf*16 + l15;
        Pf[mf] = *(const bfx8*)(Pw + row*128 + (((4*kk + l4) ^ (row & 7)) * 16));
      }
      #pragma unroll
      for (int nd = 0; nd < 4; ++nd) {
        const int dr = nd*16 + l15;
        const bfx8 Vf = *(const bfx8*)(Vt + dr*128 + (((4*kk + l4) ^ (dr & 7)) * 16));
        #pragma unroll
        for (int mf = 0; mf < 2; ++mf)
          O[mf][nd] = mfma16(Vf, Pf[mf], O[mf][nd]);
      }
    }
    __builtin_amdgcn_s_setprio(0);
  }

  // ---- epilogue: O/l, hi/lo bf16 split, bfx4 stores (d consecutive) ----
  #pragma unroll
  for (int mf = 0; mf < 2; ++mf) {
    const float inv = 1.f / l_[mf];
    const int qg = q0 + mf*16 + l15;
    #pragma unroll
    for (int nd = 0; nd < 4; ++nd) {
      bfx4 hb, lb;
      #pragma unroll
      for (int rg = 0; rg < 4; ++rg) {
        const float v = O[mf][nd][rg] * inv;
        hb[rg] = (__bf16)v;
        lb[rg] = (__bf16)(v - (float)hb[rg]);
      }
      const size_t idx = ((size_t)(b*SEQ + qg))*CH + h*DD + nd*16 + 4*l4;
      *(bfx4*)(ao_hi + idx) = hb;
      *(bfx4*)(ao_lo + idx) = lb;
    }
  }
}

// ---------------------------------------------------------------------------
extern "C" void kernel_launch(void* const* d_in, const int* in_sizes, int n_in,
                              void* d_out, int out_size, void* d_ws, size_t ws_size,
                              hipStream_t stream) {
  const float* x         = (const float*)d_in[0];
  const float* attn_bias = (const float*)d_in[1];
  const float* qkv_w     = (const float*)d_in[2];
  const float* q_bias    = (const float*)d_in[3];
  const float* v_bias    = (const float*)d_in[4];
  const float* scale_mul = (const float*)d_in[5];
  const float* proj_w    = (const float*)d_in[6];
  const float* proj_b    = (const float*)d_in[7];
  float* out = (float*)d_out;

  char* ws = (char*)d_ws;
  size_t off = 0;
  auto alloc = [&](size_t n) { char* p = ws + off; off += (n + 255) & ~(size_t)255; return p; };
  __bf16* x_h  = (__bf16*)alloc((size_t)MROWS*CH*2);
  __bf16* x_l  = (__bf16*)alloc((size_t)MROWS*CH*2);
  __bf16* w_h  = (__bf16*)alloc((size_t)3*CH*CH*2);
  __bf16* w_l  = (__bf16*)alloc((size_t)3*CH*CH*2);
  __bf16* p_h  = (__bf16*)alloc((size_t)CH*CH*2);
  __bf16* p_l  = (__bf16*)alloc((size_t)CH*CH*2);
  __bf16* qkvn = (__bf16*)alloc((size_t)2*BHLD*2);   // q,k [B,H,L,D] (normalized)
  __bf16* vt   = (__bf16*)alloc((size_t)BHLD*2);     // v   [B,H,D,L]
  __bf16* ao_h = (__bf16*)alloc((size_t)MROWS*CH*2);
  __bf16* ao_l = (__bf16*)alloc((size_t)MROWS*CH*2);
  int*    flag = (int*)alloc(256);

  split_kernel<<<MROWS*CH/4/256, 256, 0, stream>>>((const float4*)x, x_h, x_l, MROWS*CH/4);
  split_kernel<<<3*CH*CH/4/256, 256, 0, stream>>>((const float4*)qkv_w, w_h, w_l, 3*CH*CH/4);
  split_kernel<<<CH*CH/4/256, 256, 0, stream>>>((const float4*)proj_w, p_h, p_l, CH*CH/4);

  hipMemsetAsync(flag, 0, sizeof(int), stream);
  scan_nz<<<2048, 256, 0, stream>>>((const uint4*)attn_bias, SEQ*SEQ/4, flag);

  // GEMM1: [8192,3072] = x*qkv_w^T (+bias, +fused l2norm) -> q/k [B,H,L,D], v [B,H,D,L]
  gemm128<1><<<(MROWS/128)*(3*CH/128), 256, 0, stream>>>(
      x_h, x_l, w_h, w_l, 3*CH/128, CH, q_bias, v_bias, scale_mul,
      nullptr, qkvn, vt);

  attn_kernel<<<NB*NH*(SEQ/128), 256, 0, stream>>>(
      qkvn, qkvn + (size_t)BHLD, vt, attn_bias, flag, ao_h, ao_l);

  // GEMM2: d_out = attn_out * proj_w^T + proj_b
  gemm128<2><<<(MROWS/128)*(CH/128), 256, 0, stream>>>(
      ao_h, ao_l, p_h, p_l, CH/128, CH, proj_b, nullptr, nullptr,
      out, nullptr, nullptr);
}

// Round 10
// 292.984 us; speedup vs baseline: 2.1856x; 1.2853x over previous
//
#include <hip/hip_runtime.h>
#include <cstdint>

// ---------------------------------------------------------------------------
// SelfAttention (QK-l2norm variant), MI355X/gfx950.
// R10: GEMM1 switched to PLAIN bf16 (1 MFMA term): q,k are l2-normalized and
// rounded to bf16 right after, so split-precision there only chased the
// rounding floor (error analysis: post-norm element error 2e-4 plain vs
// 1.4e-4 rounding-only). 3x fewer FLOPs + 3x less LDS traffic on the largest
// kernel. GEMM2 STAYS Markidis hi/lo split (its error hits d_out directly).
// Attention unchanged (KVBLK=64, exp2 softmax, defer-rescale).
// ---------------------------------------------------------------------------

typedef __bf16 bfx8 __attribute__((ext_vector_type(8)));
typedef __bf16 bfx4 __attribute__((ext_vector_type(4)));
typedef float  f32x4 __attribute__((ext_vector_type(4)));

#define NB   4
#define NH   16
#define SEQ  2048
#define CH   1024
#define DD   64
#define MROWS (NB*SEQ)             /* 8192 */
#define BHLD  (NB*NH*SEQ*DD)       /* 8388608 */
#define LOG2E 1.44269504088896340736f

__device__ __forceinline__ void async16(void* lds, const void* g) {
  __builtin_amdgcn_global_load_lds((const __attribute__((address_space(1))) void*)g,
                                   (__attribute__((address_space(3))) void*)lds, 16, 0, 0);
}
__device__ __forceinline__ f32x4 mfma16(bfx8 a, bfx8 b, f32x4 c) {
  return __builtin_amdgcn_mfma_f32_16x16x32_bf16(a, b, c, 0, 0, 0);
}

extern "C" __device__ float __ocml_exp2_f32(float);
__device__ __forceinline__ float fexp2(float x) {
#if __has_builtin(__builtin_amdgcn_exp2f)
  return __builtin_amdgcn_exp2f(x);
#else
  return __ocml_exp2_f32(x);
#endif
}

// --------------------------- f32 -> bf16 cast (hi only) ---------------------
__global__ __launch_bounds__(256) void cast_kernel(const float4* __restrict__ src,
                                                   __bf16* __restrict__ dst, int n4) {
  int i = blockIdx.x * 256 + threadIdx.x;
  if (i >= n4) return;
  float4 v = src[i];
  float vv[4] = {v.x, v.y, v.z, v.w};
  bfx4 h;
  #pragma unroll
  for (int j = 0; j < 4; ++j) h[j] = (__bf16)vv[j];
  *(bfx4*)(dst + 4*(size_t)i) = h;
}

// --------------------------- hi/lo split (Markidis) -------------------------
__global__ __launch_bounds__(256) void split_kernel(const float4* __restrict__ src,
                                                    __bf16* __restrict__ hi,
                                                    __bf16* __restrict__ lo, int n4) {
  int i = blockIdx.x * 256 + threadIdx.x;
  if (i >= n4) return;
  float4 v = src[i];
  float vv[4] = {v.x, v.y, v.z, v.w};
  bfx4 h, l;
  #pragma unroll
  for (int j = 0; j < 4; ++j) {
    __bf16 hb = (__bf16)vv[j];
    h[j] = hb;
    l[j] = (__bf16)(vv[j] - (float)hb);
  }
  *(bfx4*)(hi + 4*(size_t)i) = h;
  *(bfx4*)(lo + 4*(size_t)i) = l;
}

// --------------------------- bias nonzero scan ------------------------------
__global__ __launch_bounds__(256) void scan_nz(const uint4* __restrict__ p, int n4,
                                               int* __restrict__ flag) {
  unsigned acc = 0;
  const int stride = gridDim.x * 256;
  for (int i = blockIdx.x * 256 + threadIdx.x; i < n4; i += stride) {
    uint4 u = p[i];
    acc |= (u.x | u.y | u.z | u.w) & 0x7fffffffu;
  }
  if (acc) atomicOr(flag, 1);
}

// ------------------- PLAIN bf16 GEMM 128x128 (qkv projection) ---------------
// C[M,N] = A[M,K]*B[N,K]^T, plain bf16. R9's proven body minus lo buffers:
// 128x128 tile, 4 waves (2x2 of 64x64), BK=32, 16KB LDS, 2 barriers/K-step,
// launch_bounds(256,2). 0-conflict chunk-XOR swizzle.
// Epilogue: +concat(q_bias,0,v_bias), FUSED l2norm (+exp(scale)*LOG2E on q);
// q/k -> [B,H,L,D] bf16, v -> [B,H,D,L].
__global__ __launch_bounds__(256, 2) void gemmq(
    const __bf16* __restrict__ Ag, const __bf16* __restrict__ Bg,
    const int Ntiles, const int K,
    const float* __restrict__ biasA, const float* __restrict__ biasB,
    const float* __restrict__ scale_mul,
    __bf16* __restrict__ outQ, __bf16* __restrict__ outV)
{
  __shared__ alignas(16) char lds[16384];   // A 8KB | B 8KB
  const int tid = threadIdx.x;
  const int lane = tid & 63, w = tid >> 6;
  const int l15 = lane & 15, l4 = lane >> 4;
  const int nwg = (int)gridDim.x;
  const int wk = (int)(blockIdx.x & 7) * (nwg >> 3) + (int)(blockIdx.x >> 3); // nwg%8==0
  const int mt = wk / Ntiles, nt = wk % Ntiles;
  const int m0 = mt * 128, n0 = nt * 128;
  const int wm = (w >> 1) * 64, wn = (w & 1) * 64;

  const f32x4 zz = {0.f, 0.f, 0.f, 0.f};
  f32x4 acc[4][4];
  #pragma unroll
  for (int a = 0; a < 4; ++a)
    #pragma unroll
    for (int b = 0; b < 4; ++b) acc[a][b] = zz;

  int st_row[2], st_c[2], st_lds[2];
  #pragma unroll
  for (int i = 0; i < 2; ++i) {
    const int s = i*256 + tid;
    st_row[i] = s >> 2;
    st_c[i]   = (s & 3) ^ ((st_row[i] >> 1) & 3);
    st_lds[i] = (i*256 + w*64) * 16;
  }

  for (int k0 = 0; k0 < K; k0 += 32) {
    __syncthreads();
    #pragma unroll
    for (int i = 0; i < 2; ++i) {
      const size_t ga = (size_t)(m0 + st_row[i]) * K + (size_t)(k0 + st_c[i]*8);
      const size_t gb = (size_t)(n0 + st_row[i]) * K + (size_t)(k0 + st_c[i]*8);
      async16(lds +        st_lds[i], Ag + ga);
      async16(lds + 8192 + st_lds[i], Bg + gb);
    }
    __syncthreads();

    bfx8 ah[4], bh[4];
    #pragma unroll
    for (int f = 0; f < 4; ++f) {
      const int ra = wm + f*16 + l15;
      ah[f] = *(const bfx8*)(lds + ra*64 + ((l4 ^ ((ra >> 1) & 3)) * 16));
      const int rb = wn + f*16 + l15;
      bh[f] = *(const bfx8*)(lds + 8192 + rb*64 + ((l4 ^ ((rb >> 1) & 3)) * 16));
    }
    __builtin_amdgcn_s_setprio(1);
    #pragma unroll
    for (int mf = 0; mf < 4; ++mf)
      #pragma unroll
      for (int nf = 0; nf < 4; ++nf)
        acc[mf][nf] = mfma16(ah[mf], bh[nf], acc[mf][nf]);
    __builtin_amdgcn_s_setprio(0);
  }

  // ---- epilogue: bias + fused l2norm + scatter (C/D col=l15, row=4*l4+rg)
  const int gcb = n0 + wn;
  const int which = gcb >> 10;                 // 0 q, 1 k, 2 v
  const int hh = (gcb & (CH-1)) >> 6;
  float smul = 1.f;
  if (which == 0) smul = __expf(fminf(scale_mul[hh], 4.605170185988091f)) * LOG2E;
  #pragma unroll
  for (int mf = 0; mf < 4; ++mf)
    #pragma unroll
    for (int rg = 0; rg < 4; ++rg) {
      #pragma unroll
      for (int nf = 0; nf < 4; ++nf) {
        const int gc = gcb + nf*16 + l15;
        acc[mf][nf][rg] += (which == 0) ? biasA[gc]
                         : ((which == 2) ? biasB[gc - 2*CH] : 0.f);
      }
      const int gr = m0 + wm + mf*16 + 4*l4 + rg;
      const int bb = gr >> 11, ll = gr & (SEQ-1);
      float sc = 1.f;
      if (which < 2) {   // fused l2norm over the 64-col head block (f32)
        float ss = 0.f;
        #pragma unroll
        for (int nf = 0; nf < 4; ++nf) ss += acc[mf][nf][rg] * acc[mf][nf][rg];
        ss += __shfl_xor(ss, 1); ss += __shfl_xor(ss, 2);
        ss += __shfl_xor(ss, 4); ss += __shfl_xor(ss, 8);
        sc = smul / fmaxf(sqrtf(ss), 1e-12f);
      }
      #pragma unroll
      for (int nf = 0; nf < 4; ++nf) {
        const float v = acc[mf][nf][rg] * sc;
        const int dd = nf*16 + l15;
        if (which < 2)
          outQ[(size_t)which*BHLD + ((size_t)((bb*NH + hh)*SEQ) + ll)*DD + dd] = (__bf16)v;
        else
          outV[((size_t)(bb*NH + hh)*DD + dd)*SEQ + ll] = (__bf16)v;
      }
    }
}

// --------------------------- split-bf16 GEMM (output proj) ------------------
// R9's proven split body: 128x128, 4 waves, BK=32, 32KB LDS, 2 barriers/K-step,
// 3 MFMA terms (al*bh, ah*bl, ah*bh). +proj_b -> f32 d_out.
__global__ __launch_bounds__(256, 2) void gemm128s(
    const __bf16* __restrict__ Agh, const __bf16* __restrict__ Agl,
    const __bf16* __restrict__ Bgh, const __bf16* __restrict__ Bgl,
    const int Ntiles, const int K,
    const float* __restrict__ biasA, float* __restrict__ outF)
{
  __shared__ alignas(16) char lds[32768];   // Ah | Al | Bh | Bl, 8KB each
  const int tid = threadIdx.x;
  const int lane = tid & 63, w = tid >> 6;
  const int l15 = lane & 15, l4 = lane >> 4;
  const int nwg = (int)gridDim.x;
  const int wk = (int)(blockIdx.x & 7) * (nwg >> 3) + (int)(blockIdx.x >> 3);
  const int mt = wk / Ntiles, nt = wk % Ntiles;
  const int m0 = mt * 128, n0 = nt * 128;
  const int wm = (w >> 1) * 64, wn = (w & 1) * 64;

  const f32x4 zz = {0.f, 0.f, 0.f, 0.f};
  f32x4 acc[4][4];
  #pragma unroll
  for (int a = 0; a < 4; ++a)
    #pragma unroll
    for (int b = 0; b < 4; ++b) acc[a][b] = zz;

  int st_row[2], st_c[2], st_lds[2];
  #pragma unroll
  for (int i = 0; i < 2; ++i) {
    const int s = i*256 + tid;
    st_row[i] = s >> 2;
    st_c[i]   = (s & 3) ^ ((st_row[i] >> 1) & 3);
    st_lds[i] = (i*256 + w*64) * 16;
  }

  for (int k0 = 0; k0 < K; k0 += 32) {
    __syncthreads();
    #pragma unroll
    for (int i = 0; i < 2; ++i) {
      const size_t ga = (size_t)(m0 + st_row[i]) * K + (size_t)(k0 + st_c[i]*8);
      const size_t gb = (size_t)(n0 + st_row[i]) * K + (size_t)(k0 + st_c[i]*8);
      async16(lds +         st_lds[i], Agh + ga);
      async16(lds +  8192 + st_lds[i], Agl + ga);
      async16(lds + 16384 + st_lds[i], Bgh + gb);
      async16(lds + 24576 + st_lds[i], Bgl + gb);
    }
    __syncthreads();

    bfx8 ah[4], al[4], bh[4], bl[4];
    #pragma unroll
    for (int f = 0; f < 4; ++f) {
      const int ra = wm + f*16 + l15;
      const int oa = ra*64 + ((l4 ^ ((ra >> 1) & 3)) * 16);
      ah[f] = *(const bfx8*)(lds + oa);
      al[f] = *(const bfx8*)(lds + 8192 + oa);
      const int rb = wn + f*16 + l15;
      const int ob = rb*64 + ((l4 ^ ((rb >> 1) & 3)) * 16);
      bh[f] = *(const bfx8*)(lds + 16384 + ob);
      bl[f] = *(const bfx8*)(lds + 24576 + ob);
    }
    __builtin_amdgcn_s_setprio(1);
    #pragma unroll
    for (int mf = 0; mf < 4; ++mf)
      #pragma unroll
      for (int nf = 0; nf < 4; ++nf) {
        acc[mf][nf] = mfma16(al[mf], bh[nf], acc[mf][nf]);
        acc[mf][nf] = mfma16(ah[mf], bl[nf], acc[mf][nf]);
        acc[mf][nf] = mfma16(ah[mf], bh[nf], acc[mf][nf]);
      }
    __builtin_amdgcn_s_setprio(0);
  }

  #pragma unroll
  for (int mf = 0; mf < 4; ++mf)
    #pragma unroll
    for (int nf = 0; nf < 4; ++nf)
      #pragma unroll
      for (int rg = 0; rg < 4; ++rg) {
        const int gr = m0 + wm + mf*16 + 4*l4 + rg;
        const int gc = n0 + wn + nf*16 + l15;
        outF[(size_t)gr*CH + gc] = acc[mf][nf][rg] + biasA[gc];
      }
}

// --------------------------- flash attention (bf16, swapped ops) ------------
// KVBLK=64: Ks 8KB, Vt 8KB, Ps 4x4KB = 32KB total. Scores in log2-units;
// exp2 softmax; defer-rescale while __all(mx - m <= 12).
__global__ __launch_bounds__(256, 2) void attn_kernel(
    const __bf16* __restrict__ qn, const __bf16* __restrict__ kn,
    const __bf16* __restrict__ vtg,
    const float* __restrict__ bias, const int* __restrict__ flag,
    __bf16* __restrict__ ao_hi, __bf16* __restrict__ ao_lo)
{
  __shared__ alignas(16) char Ks[8192];
  __shared__ alignas(16) char Vt[8192];
  __shared__ alignas(16) char Ps[16384];

  const int tid = threadIdx.x, lane = tid & 63, w = tid >> 6;
  const int l15 = lane & 15, l4 = lane >> 4;
  const int wk = (int)(blockIdx.x & 7) * 128 + (int)(blockIdx.x >> 3);
  const int qt = wk & 15, h = (wk >> 4) & 15, b = wk >> 8;
  const size_t bh = ((size_t)(b*NH + h)) * SEQ * DD;
  const int hasbias = *flag;
  char* Pw = Ps + w*4096;

  bfx8 Qf[2][2];
  const int q0 = qt*128 + w*32;
  #pragma unroll
  for (int mf = 0; mf < 2; ++mf)
    #pragma unroll
    for (int kd = 0; kd < 2; ++kd)
      Qf[mf][kd] = *(const bfx8*)(qn + bh + (size_t)(q0 + mf*16 + l15)*DD + kd*32 + l4*8);

  const f32x4 zz = {0.f, 0.f, 0.f, 0.f};
  f32x4 O[2][4];
  float m_[2] = {-1e30f, -1e30f}, l_[2] = {0.f, 0.f};
  #pragma unroll
  for (int mf = 0; mf < 2; ++mf)
    #pragma unroll
    for (int nd = 0; nd < 4; ++nd) O[mf][nd] = zz;

  for (int t = 0; t < 32; ++t) {
    __syncthreads();

    const __bf16* ksrc = kn + bh + (size_t)t*64*DD;
    #pragma unroll
    for (int i = 0; i < 2; ++i) {
      const int s = i*256 + tid;
      const int row = s >> 3;
      const int c = (s & 7) ^ (row & 7);
      async16(Ks + (size_t)(i*256 + w*64)*16, ksrc + (size_t)row*DD + c*8);
    }
    const __bf16* vsrc = vtg + bh + (size_t)t*64;
    #pragma unroll
    for (int i = 0; i < 2; ++i) {
      const int s = i*256 + tid;
      const int row = s >> 3;
      const int c = (s & 7) ^ (row & 7);
      async16(Vt + (size_t)(i*256 + w*64)*16, vsrc + (size_t)row*SEQ + c*8);
    }
    __syncthreads();

    // ---- S^T = K Q^T ----
    f32x4 ST[2][4];
    __builtin_amdgcn_s_setprio(1);
    #pragma unroll
    for (int nf = 0; nf < 4; ++nf) {
      const int r = nf*16 + l15;
      const bfx8 K0 = *(const bfx8*)(Ks + r*128 + ((l4 ^ (r & 7)) * 16));
      const bfx8 K1 = *(const bfx8*)(Ks + r*128 + (((4 + l4) ^ (r & 7)) * 16));
      #pragma unroll
      for (int mf = 0; mf < 2; ++mf) {
        f32x4 sacc = mfma16(K0, Qf[mf][0], zz);
        ST[mf][nf] = mfma16(K1, Qf[mf][1], sacc);
      }
    }
    __builtin_amdgcn_s_setprio(0);

    if (hasbias) {
      #pragma unroll
      for (int mf = 0; mf < 2; ++mf) {
        const size_t qg = (size_t)(q0 + mf*16 + l15);
        const float* bp = bias + qg*SEQ + (size_t)t*64;
        #pragma unroll
        for (int nf = 0; nf < 4; ++nf)
          #pragma unroll
          for (int rg = 0; rg < 4; ++rg)
            ST[mf][nf][rg] += bp[nf*16 + 4*l4 + rg] * LOG2E;
      }
    }

    // ---- online softmax (log2-units; defer-rescale) ----
    #pragma unroll
    for (int mf = 0; mf < 2; ++mf) {
      f32x4 mv = ST[mf][0];
      #pragma unroll
      for (int nf = 1; nf < 4; ++nf)
        #pragma unroll
        for (int rg = 0; rg < 4; ++rg) mv[rg] = fmaxf(mv[rg], ST[mf][nf][rg]);
      float mx = fmaxf(fmaxf(mv[0], mv[1]), fmaxf(mv[2], mv[3]));
      mx = fmaxf(mx, __shfl_xor(mx, 16));
      mx = fmaxf(mx, __shfl_xor(mx, 32));
      const bool skip = __all(mx - m_[mf] <= 12.0f) != 0;
      const float mn = skip ? m_[mf] : fmaxf(m_[mf], mx);
      f32x4 sv = zz;
      #pragma unroll
      for (int nf = 0; nf < 4; ++nf) {
        #pragma unroll
        for (int rg = 0; rg < 4; ++rg) {
          const float pv = fexp2(ST[mf][nf][rg] - mn);
          ST[mf][nf][rg] = pv;
          sv[rg] += pv;
        }
      }
      float rs = (sv[0] + sv[1]) + (sv[2] + sv[3]);
      rs += __shfl_xor(rs, 16);
      rs += __shfl_xor(rs, 32);
      if (skip) {
        l_[mf] += rs;
      } else {
        const float corr = fexp2(m_[mf] - mn);
        l_[mf] = l_[mf] * corr + rs;
        m_[mf] = mn;
        #pragma unroll
        for (int nd = 0; nd < 4; ++nd)
          #pragma unroll
          for (int rg = 0; rg < 4; ++rg) O[mf][nd][rg] *= corr;
      }

      const int row = mf*16 + l15;
      #pragma unroll
      for (int nf = 0; nf < 4; ++nf) {
        bfx4 p4;
        #pragma unroll
        for (int rg = 0; rg < 4; ++rg) p4[rg] = (__bf16)ST[mf][nf][rg];
        const int cpos = (2*nf + (l4 >> 1)) ^ (row & 7);
        *(bfx4*)(Pw + row*128 + cpos*16 + (l4 & 1)*8) = p4;
      }
    }

    // ---- O^T += V^T P ----
    __builtin_amdgcn_s_setprio(1);
    #pragma unroll
    for (int kk = 0; kk < 2; ++kk) {
      bfx8 Pf[2];
      #pragma unroll
      for (int mf = 0; mf < 2; ++mf) {
        const int row = mf*16 + l15;
        Pf[mf] = *(const bfx8*)(Pw + row*128 + (((4*kk + l4) ^ (row & 7)) * 16));
      }
      #pragma unroll
      for (int nd = 0; nd < 4; ++nd) {
        const int dr = nd*16 + l15;
        const bfx8 Vf = *(const bfx8*)(Vt + dr*128 + (((4*kk + l4) ^ (dr & 7)) * 16));
        #pragma unroll
        for (int mf = 0; mf < 2; ++mf)
          O[mf][nd] = mfma16(Vf, Pf[mf], O[mf][nd]);
      }
    }
    __builtin_amdgcn_s_setprio(0);
  }

  #pragma unroll
  for (int mf = 0; mf < 2; ++mf) {
    const float inv = 1.f / l_[mf];
    const int qg = q0 + mf*16 + l15;
    #pragma unroll
    for (int nd = 0; nd < 4; ++nd) {
      bfx4 hb, lb;
      #pragma unroll
      for (int rg = 0; rg < 4; ++rg) {
        const float v = O[mf][nd][rg] * inv;
        hb[rg] = (__bf16)v;
        lb[rg] = (__bf16)(v - (float)hb[rg]);
      }
      const size_t idx = ((size_t)(b*SEQ + qg))*CH + h*DD + nd*16 + 4*l4;
      *(bfx4*)(ao_hi + idx) = hb;
      *(bfx4*)(ao_lo + idx) = lb;
    }
  }
}

// ---------------------------------------------------------------------------
extern "C" void kernel_launch(void* const* d_in, const int* in_sizes, int n_in,
                              void* d_out, int out_size, void* d_ws, size_t ws_size,
                              hipStream_t stream) {
  const float* x         = (const float*)d_in[0];
  const float* attn_bias = (const float*)d_in[1];
  const float* qkv_w     = (const float*)d_in[2];
  const float* q_bias    = (const float*)d_in[3];
  const float* v_bias    = (const float*)d_in[4];
  const float* scale_mul = (const float*)d_in[5];
  const float* proj_w    = (const float*)d_in[6];
  const float* proj_b    = (const float*)d_in[7];
  float* out = (float*)d_out;

  char* ws = (char*)d_ws;
  size_t off = 0;
  auto alloc = [&](size_t n) { char* p = ws + off; off += (n + 255) & ~(size_t)255; return p; };
  __bf16* x_h  = (__bf16*)alloc((size_t)MROWS*CH*2);
  __bf16* w_h  = (__bf16*)alloc((size_t)3*CH*CH*2);
  __bf16* p_h  = (__bf16*)alloc((size_t)CH*CH*2);
  __bf16* p_l  = (__bf16*)alloc((size_t)CH*CH*2);
  __bf16* qkvn = (__bf16*)alloc((size_t)2*BHLD*2);   // q,k [B,H,L,D] (normalized)
  __bf16* vt   = (__bf16*)alloc((size_t)BHLD*2);     // v   [B,H,D,L]
  __bf16* ao_h = (__bf16*)alloc((size_t)MROWS*CH*2);
  __bf16* ao_l = (__bf16*)alloc((size_t)MROWS*CH*2);
  int*    flag = (int*)alloc(256);

  cast_kernel<<<MROWS*CH/4/256, 256, 0, stream>>>((const float4*)x, x_h, MROWS*CH/4);
  cast_kernel<<<3*CH*CH/4/256, 256, 0, stream>>>((const float4*)qkv_w, w_h, 3*CH*CH/4);
  split_kernel<<<CH*CH/4/256, 256, 0, stream>>>((const float4*)proj_w, p_h, p_l, CH*CH/4);

  hipMemsetAsync(flag, 0, sizeof(int), stream);
  scan_nz<<<2048, 256, 0, stream>>>((const uint4*)attn_bias, SEQ*SEQ/4, flag);

  // GEMM1 (plain bf16): [8192,3072] = x*qkv_w^T (+bias, +fused l2norm)
  gemmq<<<(MROWS/128)*(3*CH/128), 256, 0, stream>>>(
      x_h, w_h, 3*CH/128, CH, q_bias, v_bias, scale_mul, qkvn, vt);

  attn_kernel<<<NB*NH*(SEQ/128), 256, 0, stream>>>(
      qkvn, qkvn + (size_t)BHLD, vt, attn_bias, flag, ao_h, ao_l);

  // GEMM2 (split, fp32-accurate): d_out = attn_out * proj_w^T + proj_b
  gemm128s<<<(MROWS/128)*(CH/128), 256, 0, stream>>>(
      ao_h, ao_l, p_h, p_l, CH/128, CH, proj_b, out);
}

// Round 11
// 272.022 us; speedup vs baseline: 2.3540x; 1.0771x over previous
//
#include <hip/hip_runtime.h>
#include <cstdint>

// ---------------------------------------------------------------------------
// SelfAttention (QK-l2norm variant), MI355X/gfx950.
// R11: attention rework: (1) fixed-m softmax on the no-bias path — m = per-
// head provable score bound M_h = exp(min(scale_mul,log100))*log2e, so no
// max-reduce/rescale logic at all; (2) row-sum l via mfma(ones,P) on the idle
// MFMA pipe; (3) double-buffered K/V staging, one barrier per tile, vmcnt
// drained after a full tile of compute. GEMM1 plain bf16 + fused l2norm
// (R10-verified), GEMM2 Markidis split (fp32-accurate).
// ---------------------------------------------------------------------------

typedef __bf16 bfx8 __attribute__((ext_vector_type(8)));
typedef __bf16 bfx4 __attribute__((ext_vector_type(4)));
typedef float  f32x4 __attribute__((ext_vector_type(4)));

#define NB   4
#define NH   16
#define SEQ  2048
#define CH   1024
#define DD   64
#define MROWS (NB*SEQ)             /* 8192 */
#define BHLD  (NB*NH*SEQ*DD)       /* 8388608 */
#define LOG2E 1.44269504088896340736f

__device__ __forceinline__ void async16(void* lds, const void* g) {
  __builtin_amdgcn_global_load_lds((const __attribute__((address_space(1))) void*)g,
                                   (__attribute__((address_space(3))) void*)lds, 16, 0, 0);
}
__device__ __forceinline__ f32x4 mfma16(bfx8 a, bfx8 b, f32x4 c) {
  return __builtin_amdgcn_mfma_f32_16x16x32_bf16(a, b, c, 0, 0, 0);
}

extern "C" __device__ float __ocml_exp2_f32(float);
__device__ __forceinline__ float fexp2(float x) {
#if __has_builtin(__builtin_amdgcn_exp2f)
  return __builtin_amdgcn_exp2f(x);
#else
  return __ocml_exp2_f32(x);
#endif
}

// --------------------------- f32 -> bf16 cast (hi only) ---------------------
__global__ __launch_bounds__(256) void cast_kernel(const float4* __restrict__ src,
                                                   __bf16* __restrict__ dst, int n4) {
  int i = blockIdx.x * 256 + threadIdx.x;
  if (i >= n4) return;
  float4 v = src[i];
  float vv[4] = {v.x, v.y, v.z, v.w};
  bfx4 h;
  #pragma unroll
  for (int j = 0; j < 4; ++j) h[j] = (__bf16)vv[j];
  *(bfx4*)(dst + 4*(size_t)i) = h;
}

// --------------------------- hi/lo split (Markidis) -------------------------
__global__ __launch_bounds__(256) void split_kernel(const float4* __restrict__ src,
                                                    __bf16* __restrict__ hi,
                                                    __bf16* __restrict__ lo, int n4) {
  int i = blockIdx.x * 256 + threadIdx.x;
  if (i >= n4) return;
  float4 v = src[i];
  float vv[4] = {v.x, v.y, v.z, v.w};
  bfx4 h, l;
  #pragma unroll
  for (int j = 0; j < 4; ++j) {
    __bf16 hb = (__bf16)vv[j];
    h[j] = hb;
    l[j] = (__bf16)(vv[j] - (float)hb);
  }
  *(bfx4*)(hi + 4*(size_t)i) = h;
  *(bfx4*)(lo + 4*(size_t)i) = l;
}

// --------------------------- bias nonzero scan ------------------------------
__global__ __launch_bounds__(256) void scan_nz(const uint4* __restrict__ p, int n4,
                                               int* __restrict__ flag) {
  unsigned acc = 0;
  const int stride = gridDim.x * 256;
  for (int i = blockIdx.x * 256 + threadIdx.x; i < n4; i += stride) {
    uint4 u = p[i];
    acc |= (u.x | u.y | u.z | u.w) & 0x7fffffffu;
  }
  if (acc) atomicOr(flag, 1);
}

// ------------------- PLAIN bf16 GEMM 128x128 (qkv projection) ---------------
// R10-verified body. Epilogue: +concat(q_bias,0,v_bias), FUSED l2norm
// (+exp(scale)*LOG2E on q); q/k -> [B,H,L,D] bf16, v -> [B,H,D,L].
__global__ __launch_bounds__(256, 2) void gemmq(
    const __bf16* __restrict__ Ag, const __bf16* __restrict__ Bg,
    const int Ntiles, const int K,
    const float* __restrict__ biasA, const float* __restrict__ biasB,
    const float* __restrict__ scale_mul,
    __bf16* __restrict__ outQ, __bf16* __restrict__ outV)
{
  __shared__ alignas(16) char lds[16384];   // A 8KB | B 8KB
  const int tid = threadIdx.x;
  const int lane = tid & 63, w = tid >> 6;
  const int l15 = lane & 15, l4 = lane >> 4;
  const int nwg = (int)gridDim.x;
  const int wk = (int)(blockIdx.x & 7) * (nwg >> 3) + (int)(blockIdx.x >> 3); // nwg%8==0
  const int mt = wk / Ntiles, nt = wk % Ntiles;
  const int m0 = mt * 128, n0 = nt * 128;
  const int wm = (w >> 1) * 64, wn = (w & 1) * 64;

  const f32x4 zz = {0.f, 0.f, 0.f, 0.f};
  f32x4 acc[4][4];
  #pragma unroll
  for (int a = 0; a < 4; ++a)
    #pragma unroll
    for (int b = 0; b < 4; ++b) acc[a][b] = zz;

  int st_row[2], st_c[2], st_lds[2];
  #pragma unroll
  for (int i = 0; i < 2; ++i) {
    const int s = i*256 + tid;
    st_row[i] = s >> 2;
    st_c[i]   = (s & 3) ^ ((st_row[i] >> 1) & 3);
    st_lds[i] = (i*256 + w*64) * 16;
  }

  for (int k0 = 0; k0 < K; k0 += 32) {
    __syncthreads();
    #pragma unroll
    for (int i = 0; i < 2; ++i) {
      const size_t ga = (size_t)(m0 + st_row[i]) * K + (size_t)(k0 + st_c[i]*8);
      const size_t gb = (size_t)(n0 + st_row[i]) * K + (size_t)(k0 + st_c[i]*8);
      async16(lds +        st_lds[i], Ag + ga);
      async16(lds + 8192 + st_lds[i], Bg + gb);
    }
    __syncthreads();

    bfx8 ah[4], bh[4];
    #pragma unroll
    for (int f = 0; f < 4; ++f) {
      const int ra = wm + f*16 + l15;
      ah[f] = *(const bfx8*)(lds + ra*64 + ((l4 ^ ((ra >> 1) & 3)) * 16));
      const int rb = wn + f*16 + l15;
      bh[f] = *(const bfx8*)(lds + 8192 + rb*64 + ((l4 ^ ((rb >> 1) & 3)) * 16));
    }
    __builtin_amdgcn_s_setprio(1);
    #pragma unroll
    for (int mf = 0; mf < 4; ++mf)
      #pragma unroll
      for (int nf = 0; nf < 4; ++nf)
        acc[mf][nf] = mfma16(ah[mf], bh[nf], acc[mf][nf]);
    __builtin_amdgcn_s_setprio(0);
  }

  // ---- epilogue: bias + fused l2norm + scatter (C/D col=l15, row=4*l4+rg)
  const int gcb = n0 + wn;
  const int which = gcb >> 10;                 // 0 q, 1 k, 2 v
  const int hh = (gcb & (CH-1)) >> 6;
  float smul = 1.f;
  if (which == 0) smul = __expf(fminf(scale_mul[hh], 4.605170185988091f)) * LOG2E;
  #pragma unroll
  for (int mf = 0; mf < 4; ++mf)
    #pragma unroll
    for (int rg = 0; rg < 4; ++rg) {
      #pragma unroll
      for (int nf = 0; nf < 4; ++nf) {
        const int gc = gcb + nf*16 + l15;
        acc[mf][nf][rg] += (which == 0) ? biasA[gc]
                         : ((which == 2) ? biasB[gc - 2*CH] : 0.f);
      }
      const int gr = m0 + wm + mf*16 + 4*l4 + rg;
      const int bb = gr >> 11, ll = gr & (SEQ-1);
      float sc = 1.f;
      if (which < 2) {   // fused l2norm over the 64-col head block (f32)
        float ss = 0.f;
        #pragma unroll
        for (int nf = 0; nf < 4; ++nf) ss += acc[mf][nf][rg] * acc[mf][nf][rg];
        ss += __shfl_xor(ss, 1); ss += __shfl_xor(ss, 2);
        ss += __shfl_xor(ss, 4); ss += __shfl_xor(ss, 8);
        sc = smul / fmaxf(sqrtf(ss), 1e-12f);
      }
      #pragma unroll
      for (int nf = 0; nf < 4; ++nf) {
        const float v = acc[mf][nf][rg] * sc;
        const int dd = nf*16 + l15;
        if (which < 2)
          outQ[(size_t)which*BHLD + ((size_t)((bb*NH + hh)*SEQ) + ll)*DD + dd] = (__bf16)v;
        else
          outV[((size_t)(bb*NH + hh)*DD + dd)*SEQ + ll] = (__bf16)v;
      }
    }
}

// --------------------------- split-bf16 GEMM (output proj) ------------------
__global__ __launch_bounds__(256, 2) void gemm128s(
    const __bf16* __restrict__ Agh, const __bf16* __restrict__ Agl,
    const __bf16* __restrict__ Bgh, const __bf16* __restrict__ Bgl,
    const int Ntiles, const int K,
    const float* __restrict__ biasA, float* __restrict__ outF)
{
  __shared__ alignas(16) char lds[32768];   // Ah | Al | Bh | Bl, 8KB each
  const int tid = threadIdx.x;
  const int lane = tid & 63, w = tid >> 6;
  const int l15 = lane & 15, l4 = lane >> 4;
  const int nwg = (int)gridDim.x;
  const int wk = (int)(blockIdx.x & 7) * (nwg >> 3) + (int)(blockIdx.x >> 3);
  const int mt = wk / Ntiles, nt = wk % Ntiles;
  const int m0 = mt * 128, n0 = nt * 128;
  const int wm = (w >> 1) * 64, wn = (w & 1) * 64;

  const f32x4 zz = {0.f, 0.f, 0.f, 0.f};
  f32x4 acc[4][4];
  #pragma unroll
  for (int a = 0; a < 4; ++a)
    #pragma unroll
    for (int b = 0; b < 4; ++b) acc[a][b] = zz;

  int st_row[2], st_c[2], st_lds[2];
  #pragma unroll
  for (int i = 0; i < 2; ++i) {
    const int s = i*256 + tid;
    st_row[i] = s >> 2;
    st_c[i]   = (s & 3) ^ ((st_row[i] >> 1) & 3);
    st_lds[i] = (i*256 + w*64) * 16;
  }

  for (int k0 = 0; k0 < K; k0 += 32) {
    __syncthreads();
    #pragma unroll
    for (int i = 0; i < 2; ++i) {
      const size_t ga = (size_t)(m0 + st_row[i]) * K + (size_t)(k0 + st_c[i]*8);
      const size_t gb = (size_t)(n0 + st_row[i]) * K + (size_t)(k0 + st_c[i]*8);
      async16(lds +         st_lds[i], Agh + ga);
      async16(lds +  8192 + st_lds[i], Agl + ga);
      async16(lds + 16384 + st_lds[i], Bgh + gb);
      async16(lds + 24576 + st_lds[i], Bgl + gb);
    }
    __syncthreads();

    bfx8 ah[4], al[4], bh[4], bl[4];
    #pragma unroll
    for (int f = 0; f < 4; ++f) {
      const int ra = wm + f*16 + l15;
      const int oa = ra*64 + ((l4 ^ ((ra >> 1) & 3)) * 16);
      ah[f] = *(const bfx8*)(lds + oa);
      al[f] = *(const bfx8*)(lds + 8192 + oa);
      const int rb = wn + f*16 + l15;
      const int ob = rb*64 + ((l4 ^ ((rb >> 1) & 3)) * 16);
      bh[f] = *(const bfx8*)(lds + 16384 + ob);
      bl[f] = *(const bfx8*)(lds + 24576 + ob);
    }
    __builtin_amdgcn_s_setprio(1);
    #pragma unroll
    for (int mf = 0; mf < 4; ++mf)
      #pragma unroll
      for (int nf = 0; nf < 4; ++nf) {
        acc[mf][nf] = mfma16(al[mf], bh[nf], acc[mf][nf]);
        acc[mf][nf] = mfma16(ah[mf], bl[nf], acc[mf][nf]);
        acc[mf][nf] = mfma16(ah[mf], bh[nf], acc[mf][nf]);
      }
    __builtin_amdgcn_s_setprio(0);
  }

  #pragma unroll
  for (int mf = 0; mf < 4; ++mf)
    #pragma unroll
    for (int nf = 0; nf < 4; ++nf)
      #pragma unroll
      for (int rg = 0; rg < 4; ++rg) {
        const int gr = m0 + wm + mf*16 + 4*l4 + rg;
        const int gc = n0 + wn + nf*16 + l15;
        outF[(size_t)gr*CH + gc] = acc[mf][nf][rg] + biasA[gc];
      }
}

// --------------------------- flash attention (bf16, swapped ops) ------------
// KVBLK=64, double-buffered Ks/Vt (2x8KB each) + Ps 16KB = 48KB -> 3 blk/CU.
// One barrier per tile; stage(t+1) issued at tile top, vmcnt(0) drained after
// a full tile of compute. No-bias path: fixed-m softmax (m = per-head bound
// M_h, no max-reduce/rescale) + row-sum l via mfma(ones, P). Bias path keeps
// online-max softmax.
__global__ __launch_bounds__(256, 2) void attn_kernel(
    const __bf16* __restrict__ qn, const __bf16* __restrict__ kn,
    const __bf16* __restrict__ vtg, const float* __restrict__ scale_mul,
    const float* __restrict__ bias, const int* __restrict__ flag,
    __bf16* __restrict__ ao_hi, __bf16* __restrict__ ao_lo)
{
  __shared__ alignas(16) char Ks[2][8192];
  __shared__ alignas(16) char Vt[2][8192];
  __shared__ alignas(16) char Ps[16384];

  const int tid = threadIdx.x, lane = tid & 63, w = tid >> 6;
  const int l15 = lane & 15, l4 = lane >> 4;
  const int wk = (int)(blockIdx.x & 7) * 128 + (int)(blockIdx.x >> 3);
  const int qt = wk & 15, h = (wk >> 4) & 15, b = wk >> 8;
  const size_t bh = ((size_t)(b*NH + h)) * SEQ * DD;
  const int hasbias = *flag;
  char* Pw = Ps + w*4096;

  // per-head provable score bound in log2 units (q scaled by sm*LOG2E, |cos|<=1)
  const float Mh = __expf(fminf(scale_mul[h], 4.605170185988091f)) * LOG2E * 1.01f;

  // Q fragments (B-operand: col=lane&15=q, k=8*(lane>>4)+j)
  bfx8 Qf[2][2];
  const int q0 = qt*128 + w*32;
  #pragma unroll
  for (int mf = 0; mf < 2; ++mf)
    #pragma unroll
    for (int kd = 0; kd < 2; ++kd)
      Qf[mf][kd] = *(const bfx8*)(qn + bh + (size_t)(q0 + mf*16 + l15)*DD + kd*32 + l4*8);

  bfx8 ones;
  #pragma unroll
  for (int j = 0; j < 8; ++j) ones[j] = (__bf16)1.0f;

  const f32x4 zz = {0.f, 0.f, 0.f, 0.f};
  f32x4 O[2][4];
  f32x4 lsum[2] = {zz, zz};
  float m_[2] = {-1e30f, -1e30f}, l_[2] = {0.f, 0.f};
  #pragma unroll
  for (int mf = 0; mf < 2; ++mf)
    #pragma unroll
    for (int nd = 0; nd < 4; ++nd) O[mf][nd] = zz;

  auto stage = [&](int t, int buf) {
    const __bf16* ksrc = kn + bh + (size_t)t*64*DD;
    const __bf16* vsrc = vtg + bh + (size_t)t*64;
    #pragma unroll
    for (int i = 0; i < 2; ++i) {
      const int s = i*256 + tid;
      const int row = s >> 3;
      const int c = (s & 7) ^ (row & 7);
      async16(Ks[buf] + (size_t)(i*256 + w*64)*16, ksrc + (size_t)row*DD + c*8);
      async16(Vt[buf] + (size_t)(i*256 + w*64)*16, vsrc + (size_t)row*SEQ + c*8);
    }
  };

  stage(0, 0);
  asm volatile("s_waitcnt vmcnt(0)" ::: "memory");
  __builtin_amdgcn_s_barrier();

  #pragma unroll 1
  for (int t = 0; t < 32; ++t) {
    const int cur = t & 1;
    if (t + 1 < 32) stage(t + 1, cur ^ 1);   // overlaps with tile-t compute

    // ---- S^T = K Q^T : lane holds q=l15(+16mf), k=16nf+4*l4+rg ----
    f32x4 ST[2][4];
    __builtin_amdgcn_s_setprio(1);
    #pragma unroll
    for (int nf = 0; nf < 4; ++nf) {
      const int r = nf*16 + l15;
      const bfx8 K0 = *(const bfx8*)(Ks[cur] + r*128 + ((l4 ^ (r & 7)) * 16));
      const bfx8 K1 = *(const bfx8*)(Ks[cur] + r*128 + (((4 + l4) ^ (r & 7)) * 16));
      #pragma unroll
      for (int mf = 0; mf < 2; ++mf) {
        f32x4 sacc = mfma16(K0, Qf[mf][0], zz);
        ST[mf][nf] = mfma16(K1, Qf[mf][1], sacc);
      }
    }
    __builtin_amdgcn_s_setprio(0);

    if (!hasbias) {
      // ---- fixed-m softmax: p = exp2(s - Mh); sum via MFMA below ----
      #pragma unroll
      for (int mf = 0; mf < 2; ++mf) {
        const int row = mf*16 + l15;
        #pragma unroll
        for (int nf = 0; nf < 4; ++nf) {
          bfx4 p4;
          #pragma unroll
          for (int rg = 0; rg < 4; ++rg)
            p4[rg] = (__bf16)fexp2(ST[mf][nf][rg] - Mh);
          const int cpos = (2*nf + (l4 >> 1)) ^ (row & 7);
          *(bfx4*)(Pw + row*128 + cpos*16 + (l4 & 1)*8) = p4;
        }
      }
    } else {
      // ---- online-max softmax (bias path) ----
      #pragma unroll
      for (int mf = 0; mf < 2; ++mf) {
        const size_t qg = (size_t)(q0 + mf*16 + l15);
        const float* bp = bias + qg*SEQ + (size_t)t*64;
        #pragma unroll
        for (int nf = 0; nf < 4; ++nf)
          #pragma unroll
          for (int rg = 0; rg < 4; ++rg)
            ST[mf][nf][rg] += bp[nf*16 + 4*l4 + rg] * LOG2E;

        f32x4 mv = ST[mf][0];
        #pragma unroll
        for (int nf = 1; nf < 4; ++nf)
          #pragma unroll
          for (int rg = 0; rg < 4; ++rg) mv[rg] = fmaxf(mv[rg], ST[mf][nf][rg]);
        float mx = fmaxf(fmaxf(mv[0], mv[1]), fmaxf(mv[2], mv[3]));
        mx = fmaxf(mx, __shfl_xor(mx, 16));
        mx = fmaxf(mx, __shfl_xor(mx, 32));
        const bool skip = __all(mx - m_[mf] <= 12.0f) != 0;
        const float mn = skip ? m_[mf] : fmaxf(m_[mf], mx);
        f32x4 sv = zz;
        #pragma unroll
        for (int nf = 0; nf < 4; ++nf)
          #pragma unroll
          for (int rg = 0; rg < 4; ++rg) {
            const float pv = fexp2(ST[mf][nf][rg] - mn);
            ST[mf][nf][rg] = pv;
            sv[rg] += pv;
          }
        float rs = (sv[0] + sv[1]) + (sv[2] + sv[3]);
        rs += __shfl_xor(rs, 16);
        rs += __shfl_xor(rs, 32);
        if (skip) {
          l_[mf] += rs;
        } else {
          const float corr = fexp2(m_[mf] - mn);
          l_[mf] = l_[mf] * corr + rs;
          m_[mf] = mn;
          #pragma unroll
          for (int nd = 0; nd < 4; ++nd)
            #pragma unroll
            for (int rg = 0; rg < 4; ++rg) O[mf][nd][rg] *= corr;
        }
        const int row = mf*16 + l15;
        #pragma unroll
        for (int nf = 0; nf < 4; ++nf) {
          bfx4 p4;
          #pragma unroll
          for (int rg = 0; rg < 4; ++rg) p4[rg] = (__bf16)ST[mf][nf][rg];
          const int cpos = (2*nf + (l4 >> 1)) ^ (row & 7);
          *(bfx4*)(Pw + row*128 + cpos*16 + (l4 & 1)*8) = p4;
        }
      }
    }

    // ---- O^T += V^T P (+ l row-sums via ones-MFMA on fast path) ----
    __builtin_amdgcn_s_setprio(1);
    #pragma unroll
    for (int kk = 0; kk < 2; ++kk) {
      bfx8 Pf[2];
      #pragma unroll
      for (int mf = 0; mf < 2; ++mf) {
        const int row = mf*16 + l15;
        Pf[mf] = *(const bfx8*)(Pw + row*128 + (((4*kk + l4) ^ (row & 7)) * 16));
      }
      #pragma unroll
      for (int nd = 0; nd < 4; ++nd) {
        const int dr = nd*16 + l15;
        const bfx8 Vf = *(const bfx8*)(Vt[cur] + dr*128 + (((4*kk + l4) ^ (dr & 7)) * 16));
        #pragma unroll
        for (int mf = 0; mf < 2; ++mf)
          O[mf][nd] = mfma16(Vf, Pf[mf], O[mf][nd]);
      }
      if (!hasbias) {
        lsum[0] = mfma16(ones, Pf[0], lsum[0]);
        lsum[1] = mfma16(ones, Pf[1], lsum[1]);
      }
    }
    __builtin_amdgcn_s_setprio(0);

    asm volatile("s_waitcnt vmcnt(0)" ::: "memory");   // stage(t+1) landed long ago
    __builtin_amdgcn_s_barrier();                      // all waves done with buf cur
  }

  if (!hasbias) { l_[0] = lsum[0][0]; l_[1] = lsum[1][0]; }

  // ---- epilogue: O/l, hi/lo bf16 split, bfx4 stores (d consecutive) ----
  #pragma unroll
  for (int mf = 0; mf < 2; ++mf) {
    const float inv = 1.f / l_[mf];
    const int qg = q0 + mf*16 + l15;
    #pragma unroll
    for (int nd = 0; nd < 4; ++nd) {
      bfx4 hb, lb;
      #pragma unroll
      for (int rg = 0; rg < 4; ++rg) {
        const float v = O[mf][nd][rg] * inv;
        hb[rg] = (__bf16)v;
        lb[rg] = (__bf16)(v - (float)hb[rg]);
      }
      const size_t idx = ((size_t)(b*SEQ + qg))*CH + h*DD + nd*16 + 4*l4;
      *(bfx4*)(ao_hi + idx) = hb;
      *(bfx4*)(ao_lo + idx) = lb;
    }
  }
}

// ---------------------------------------------------------------------------
extern "C" void kernel_launch(void* const* d_in, const int* in_sizes, int n_in,
                              void* d_out, int out_size, void* d_ws, size_t ws_size,
                              hipStream_t stream) {
  const float* x         = (const float*)d_in[0];
  const float* attn_bias = (const float*)d_in[1];
  const float* qkv_w     = (const float*)d_in[2];
  const float* q_bias    = (const float*)d_in[3];
  const float* v_bias    = (const float*)d_in[4];
  const float* scale_mul = (const float*)d_in[5];
  const float* proj_w    = (const float*)d_in[6];
  const float* proj_b    = (const float*)d_in[7];
  float* out = (float*)d_out;

  char* ws = (char*)d_ws;
  size_t off = 0;
  auto alloc = [&](size_t n) { char* p = ws + off; off += (n + 255) & ~(size_t)255; return p; };
  __bf16* x_h  = (__bf16*)alloc((size_t)MROWS*CH*2);
  __bf16* w_h  = (__bf16*)alloc((size_t)3*CH*CH*2);
  __bf16* p_h  = (__bf16*)alloc((size_t)CH*CH*2);
  __bf16* p_l  = (__bf16*)alloc((size_t)CH*CH*2);
  __bf16* qkvn = (__bf16*)alloc((size_t)2*BHLD*2);   // q,k [B,H,L,D] (normalized)
  __bf16* vt   = (__bf16*)alloc((size_t)BHLD*2);     // v   [B,H,D,L]
  __bf16* ao_h = (__bf16*)alloc((size_t)MROWS*CH*2);
  __bf16* ao_l = (__bf16*)alloc((size_t)MROWS*CH*2);
  int*    flag = (int*)alloc(256);

  cast_kernel<<<MROWS*CH/4/256, 256, 0, stream>>>((const float4*)x, x_h, MROWS*CH/4);
  cast_kernel<<<3*CH*CH/4/256, 256, 0, stream>>>((const float4*)qkv_w, w_h, 3*CH*CH/4);
  split_kernel<<<CH*CH/4/256, 256, 0, stream>>>((const float4*)proj_w, p_h, p_l, CH*CH/4);

  hipMemsetAsync(flag, 0, sizeof(int), stream);
  scan_nz<<<2048, 256, 0, stream>>>((const uint4*)attn_bias, SEQ*SEQ/4, flag);

  // GEMM1 (plain bf16): [8192,3072] = x*qkv_w^T (+bias, +fused l2norm)
  gemmq<<<(MROWS/128)*(3*CH/128), 256, 0, stream>>>(
      x_h, w_h, 3*CH/128, CH, q_bias, v_bias, scale_mul, qkvn, vt);

  attn_kernel<<<NB*NH*(SEQ/128), 256, 0, stream>>>(
      qkvn, qkvn + (size_t)BHLD, vt, scale_mul, attn_bias, flag, ao_h, ao_l);

  // GEMM2 (split, fp32-accurate): d_out = attn_out * proj_w^T + proj_b
  gemm128s<<<(MROWS/128)*(CH/128), 256, 0, stream>>>(
      ao_h, ao_l, p_h, p_l, CH/128, CH, proj_b, out);
}